// Round 6
// baseline (324.052 us; speedup 1.0000x reference)
//
#include <hip/hip_runtime.h>
#include <hip/hip_bf16.h>
#include <cstdint>

#define BATCH 8192
#define IN_F  4096
#define OUT_F 128
// float32-rounded decay constants (tau_fac=100, tau_dep=200)
#define FD 0.99004983374916811f
#define DD 0.99501247919268232f

typedef __attribute__((ext_vector_type(4))) float f32x4;
typedef __attribute__((ext_vector_type(8))) float f32x8;
typedef __attribute__((ext_vector_type(8))) short bf16x8;

__device__ __forceinline__ unsigned short f2bf(float f){
  union { float f; unsigned u; } v; v.f = f;
  unsigned u = v.u;
  return (unsigned short)((u + 0x7FFFu + ((u >> 16) & 1u)) >> 16);  // RNE
}

// Single fused kernel. 512 thr = 8 waves. Block owns 16 rows x full K=4096.
// Wave wv owns k-slice [wv*512, wv*512+512) = 16 k-steps of 32: loads pre/u/x
// directly in MFMA A-fragment layout (lane l -> row l&15, k-chunk (l>>4)*8),
// STP update in registers, r=u*x*s packed to bf16, B-fragments converted
// in-register from L2-resident w. No d_ws, no atomics, no memset; one
// end-of-kernel LDS reduction over the 8 waves' partials, direct stores.
__global__ __launch_bounds__(512, 4) void stp_fused3(
    const float* __restrict__ pre, const float* __restrict__ uin,
    const float* __restrict__ xin, const float* __restrict__ w,
    float* __restrict__ out, float* __restrict__ un_out, float* __restrict__ xn_out)
{
  __shared__ float red[8][16 * OUT_F];   // 64 KB -> 2 blocks/CU

  const int tid = threadIdx.x;
  const int wv  = tid >> 6;
  const int l   = tid & 63;
  const int rowBase = blockIdx.x * 16;
  const size_t base = (size_t)(rowBase + (l & 15)) * IN_F + wv * 512 + ((l >> 4) << 3);

  f32x4 acc[8];
  #pragma unroll
  for (int ct = 0; ct < 8; ++ct) acc[ct] = (f32x4){0.f,0.f,0.f,0.f};

  // prologue: k-step 0's A inputs
  f32x8 sC = *reinterpret_cast<const f32x8*>(pre + base);
  f32x8 uC = *reinterpret_cast<const f32x8*>(uin + base);
  f32x8 xC = *reinterpret_cast<const f32x8*>(xin + base);

  for (int ks = 0; ks < 16; ++ks){
    const size_t g   = base + (size_t)(ks << 5);
    const int    gks = (wv << 4) + ks;              // global k-step 0..127
    const int    kg  = (gks << 5) + ((l >> 4) << 3);

    // ---- B-fragments straight from w (f32 -> bf16 in-register) ----
    bf16x8 bf[8];
    #pragma unroll
    for (int ct = 0; ct < 8; ++ct){
      const int r0 = ct * 16 + (l & 15);
      const f32x4* p = reinterpret_cast<const f32x4*>(w + (size_t)r0 * IN_F + kg);
      f32x4 a = p[0], b = p[1];
      union { bf16x8 v; unsigned short s[8]; } t;
      t.s[0]=f2bf(a[0]); t.s[1]=f2bf(a[1]); t.s[2]=f2bf(a[2]); t.s[3]=f2bf(a[3]);
      t.s[4]=f2bf(b[0]); t.s[5]=f2bf(b[1]); t.s[6]=f2bf(b[2]); t.s[7]=f2bf(b[3]);
      bf[ct] = t.v;
    }

    // ---- prefetch next k-step's A inputs (ILP under this iter's work) ----
    f32x8 sN, uN, xN;
    if (ks < 15){
      const size_t gn = g + 32;
      sN = *reinterpret_cast<const f32x8*>(pre + gn);
      uN = *reinterpret_cast<const f32x8*>(uin + gn);
      xN = *reinterpret_cast<const f32x8*>(xin + gn);
    }

    // ---- elementwise: STP update + A-fragment r = u*x*s in bf16 ----
    f32x8 un, xn;
    union { bf16x8 v; unsigned short s[8]; } af;
    #pragma unroll
    for (int j = 0; j < 8; ++j){
      const float s = sC[j], u = uC[j], x = xC[j];
      af.s[j] = f2bf(u * x * s);
      const float ufd = u * FD;
      const float unj = ufd + 0.5f * (1.0f - ufd) * s;
      un[j] = unj;
      xn[j] = x * DD + (1.0f - x) * DD * (1.0f - s * unj);
    }
    // nontemporal: un/xn are never re-read — keep them out of L2/L3 so the
    // pre/u/x read streams keep the cache capacity
    __builtin_nontemporal_store(un, reinterpret_cast<f32x8*>(un_out + g));
    __builtin_nontemporal_store(xn, reinterpret_cast<f32x8*>(xn_out + g));

    // ---- MFMA: 8 col-tiles ----
    #pragma unroll
    for (int ct = 0; ct < 8; ++ct)
      acc[ct] = __builtin_amdgcn_mfma_f32_16x16x32_bf16(af.v, bf[ct], acc[ct], 0, 0, 0);

    sC = sN; uC = uN; xC = xN;
  }

  // ---- wave partials -> LDS (C/D: row=(l>>4)*4+rg, col=ct*16+(l&15)) ----
  #pragma unroll
  for (int ct = 0; ct < 8; ++ct){
    #pragma unroll
    for (int rg = 0; rg < 4; ++rg){
      red[wv][(((l >> 4) << 2) + rg) * OUT_F + ct * 16 + (l & 15)] = acc[ct][rg];
    }
  }
  __syncthreads();

  // ---- 512 threads x 4 contiguous floats: sum 8 partials, store once ----
  const int e = tid << 2;
  f32x4 sum = *reinterpret_cast<const f32x4*>(&red[0][e]);
  #pragma unroll
  for (int wq = 1; wq < 8; ++wq)
    sum += *reinterpret_cast<const f32x4*>(&red[wq][e]);
  *reinterpret_cast<f32x4*>(out + (size_t)rowBase * OUT_F + e) = sum;
}

extern "C" void kernel_launch(void* const* d_in, const int* in_sizes, int n_in,
                              void* d_out, int out_size, void* d_ws, size_t ws_size,
                              hipStream_t stream){
  const float* pre = (const float*)d_in[0];
  const float* w   = (const float*)d_in[1];
  const float* u   = (const float*)d_in[2];
  const float* x   = (const float*)d_in[3];
  float* out    = (float*)d_out;
  float* un_out = out + (size_t)BATCH * OUT_F;
  float* xn_out = un_out + (size_t)BATCH * IN_F;

  stp_fused3<<<BATCH / 16, 512, 0, stream>>>(pre, u, x, w, out, un_out, xn_out);
}

// Round 7
// 163.268 us; speedup vs baseline: 1.9848x; 1.9848x over previous
//
#include <hip/hip_runtime.h>
#include <hip/hip_bf16.h>
#include <cstdint>

#define BATCH 8192
#define IN_F  4096
#define OUT_F 128
#define KSPLIT 4
#define KSL    (IN_F / KSPLIT)   // 1024 k per block
#define CH     256               // k per chunk
#define NCHUNK (KSL / CH)        // 4
// float32-rounded decay constants (tau_fac=100, tau_dep=200)
#define FD 0.99004983374916811f
#define DD 0.99501247919268232f

typedef __attribute__((ext_vector_type(4))) float f32x4;
typedef __attribute__((ext_vector_type(8))) float f32x8;
typedef __attribute__((ext_vector_type(8))) short bf16x8;

__device__ __forceinline__ unsigned short f2bf(float f){
  union { float f; unsigned u; } v; v.f = f;
  unsigned u = v.u;
  return (unsigned short)((u + 0x7FFFu + ((u >> 16) & 1u)) >> 16);  // RNE
}

// Pre-shuffle weight[128][4096] f32 -> fragment-major bf16 (proven R1-R4).
// Frag id f = (ks*8 + ct)*64 + l ; lane l holds weight[ct*16+(l&15)][ks*32+(l>>4)*8 + j]
__global__ __launch_bounds__(256) void prep_weight_kernel(const float* __restrict__ w,
                                                          unsigned short* __restrict__ wf){
  const int f  = blockIdx.x * 256 + threadIdx.x;   // 0..65535
  const int l  = f & 63;
  const int ct = (f >> 6) & 7;
  const int ks = f >> 9;                           // 0..127
  const int row = ct * 16 + (l & 15);
  const int k   = ks * 32 + ((l >> 4) << 3);
  const f32x4* src = reinterpret_cast<const f32x4*>(w + (size_t)row * IN_F + k);
  f32x4 a = src[0], b = src[1];
  union { bf16x8 v; unsigned short s[8]; } o;
  o.s[0]=f2bf(a[0]); o.s[1]=f2bf(a[1]); o.s[2]=f2bf(a[2]); o.s[3]=f2bf(a[3]);
  o.s[4]=f2bf(b[0]); o.s[5]=f2bf(b[1]); o.s[6]=f2bf(b[2]); o.s[7]=f2bf(b[3]);
  *reinterpret_cast<bf16x8*>(wf + (size_t)f * 8) = o.v;
}

// elementwise helper: one f32x8 triple -> un/xn stores + packed bf16 r (16B)
__device__ __forceinline__ uint4 stp_ew(const f32x8 s8, const f32x8 u8, const f32x8 x8,
                                        float* __restrict__ un_p, float* __restrict__ xn_p){
  f32x8 un, xn;
  unsigned short rb[8];
  #pragma unroll
  for (int j = 0; j < 8; ++j){
    const float s = s8[j], u = u8[j], x = x8[j];
    rb[j] = f2bf(u * x * s);
    const float ufd = u * FD;
    const float unj = ufd + 0.5f * (1.0f - ufd) * s;
    un[j] = unj;
    xn[j] = x * DD + (1.0f - x) * DD * (1.0f - s * unj);
  }
  *reinterpret_cast<f32x8*>(un_p) = un;
  *reinterpret_cast<f32x8*>(xn_p) = xn;
  uint4 pk;
  pk.x = (unsigned)rb[0] | ((unsigned)rb[1] << 16);
  pk.y = (unsigned)rb[2] | ((unsigned)rb[3] << 16);
  pk.z = (unsigned)rb[4] | ((unsigned)rb[5] << 16);
  pk.w = (unsigned)rb[6] | ((unsigned)rb[7] << 16);
  return pk;
}

// Fused kernel with DRAM-friendly flat loads + LDS bounce to MFMA layout.
// Block: 256 thr = 4 waves, 16 rows x 1024-K slice, 4 chunks of 256 k.
// Loads/stores: lane l -> row 4*wv + (l>>5) (+2 for 2nd instr), k=(l&31)*8
//   => every vmem instruction covers 2 rows x 1KB contiguous runs.
// r (bf16) goes to XOR-swizzled LDS tile [16][256]; MFMA A-frags read from LDS.
template<bool WS>
__global__ __launch_bounds__(256, 4) void stp_fused4(
    const float* __restrict__ pre, const float* __restrict__ uin,
    const float* __restrict__ xin, const float* __restrict__ w,
    const unsigned short* __restrict__ wf,
    float* __restrict__ out, float* __restrict__ un_out, float* __restrict__ xn_out)
{
  __shared__ unsigned char rbuf[2][16 * CH * 2];   // 2 x 8 KB

  const int tid = threadIdx.x;
  const int wv  = tid >> 6;
  const int l   = tid & 63;
  const int ksl     = blockIdx.x & (KSPLIT - 1);
  const int rowBase = (blockIdx.x >> 2) * 16;
  const int k0      = ksl * KSL;

  // flat-load geometry (2 rows per instruction, 1KB run per row)
  const int rl0 = 4 * wv + (l >> 5);               // local row for instr h=0
  const size_t g0 = (size_t)(rowBase + rl0) * IN_F + k0 + (size_t)(l & 31) * 8;
  const size_t rowStride2 = (size_t)2 * IN_F;      // h=1 rows are rl0+2

  // LDS write byte offsets (full logical addr, then XOR swizzle bits 4-6)
  const int wb0 = ((rl0    ) * 512 + (l & 31) * 16) ^ (((rl0    ) & 7) << 4);
  const int wb1 = ((rl0 + 2) * 512 + (l & 31) * 16) ^ (((rl0 + 2) & 7) << 4);

  // A-fragment read geometry: lane l -> row l&15, k-chunk (l>>4)*8
  const int ar  = l & 15;
  const int akc = (l >> 4) * 16;                   // byte offset within 64B k-step

  f32x4 acc0 = {0.f,0.f,0.f,0.f}, acc1 = {0.f,0.f,0.f,0.f};

  // prologue: issue chunk 0 loads
  f32x8 sA0 = *reinterpret_cast<const f32x8*>(pre + g0);
  f32x8 sA1 = *reinterpret_cast<const f32x8*>(pre + g0 + rowStride2);
  f32x8 uA0 = *reinterpret_cast<const f32x8*>(uin + g0);
  f32x8 uA1 = *reinterpret_cast<const f32x8*>(uin + g0 + rowStride2);
  f32x8 xA0 = *reinterpret_cast<const f32x8*>(xin + g0);
  f32x8 xA1 = *reinterpret_cast<const f32x8*>(xin + g0 + rowStride2);

  for (int c = 0; c < NCHUNK; ++c){
    const size_t gc = g0 + (size_t)c * CH;

    // issue next chunk's loads first — a full iteration of slack
    f32x8 sB0, sB1, uB0, uB1, xB0, xB1;
    if (c + 1 < NCHUNK){
      const size_t gn = g0 + (size_t)(c + 1) * CH;
      sB0 = *reinterpret_cast<const f32x8*>(pre + gn);
      sB1 = *reinterpret_cast<const f32x8*>(pre + gn + rowStride2);
      uB0 = *reinterpret_cast<const f32x8*>(uin + gn);
      uB1 = *reinterpret_cast<const f32x8*>(uin + gn + rowStride2);
      xB0 = *reinterpret_cast<const f32x8*>(xin + gn);
      xB1 = *reinterpret_cast<const f32x8*>(xin + gn + rowStride2);
    }

    // elementwise + un/xn stores (1KB runs) + r -> swizzled LDS
    uint4 p0 = stp_ew(sA0, uA0, xA0, un_out + gc, xn_out + gc);
    uint4 p1 = stp_ew(sA1, uA1, xA1, un_out + gc + rowStride2, xn_out + gc + rowStride2);
    *reinterpret_cast<uint4*>(&rbuf[c & 1][wb0]) = p0;
    *reinterpret_cast<uint4*>(&rbuf[c & 1][wb1]) = p1;

    __syncthreads();

    // MFMA phase: 8 k-steps of 32; wave wv owns col-tiles 2wv, 2wv+1
    const unsigned char* buf = rbuf[c & 1];
    #pragma unroll
    for (int ks = 0; ks < 8; ++ks){
      const int rb = (ar * 512 + ks * 64 + akc) ^ ((ar & 7) << 4);
      bf16x8 af = *reinterpret_cast<const bf16x8*>(buf + rb);
      const int gks = (k0 >> 5) + c * 8 + ks;      // global k-step 0..127
      bf16x8 b0, b1;
      if (WS){
        const bf16x8* wfp = reinterpret_cast<const bf16x8*>(wf);
        b0 = wfp[(size_t)((gks * 8 + 2 * wv    ) << 6) + l];
        b1 = wfp[(size_t)((gks * 8 + 2 * wv + 1) << 6) + l];
      } else {
        const int kg = gks * 32 + ((l >> 4) << 3);
        const int r0 = (2 * wv) * 16 + (l & 15);
        const f32x4* q0 = reinterpret_cast<const f32x4*>(w + (size_t)r0 * IN_F + kg);
        const f32x4* q1 = reinterpret_cast<const f32x4*>(w + (size_t)(r0 + 16) * IN_F + kg);
        f32x4 a0 = q0[0], a1 = q0[1], c0 = q1[0], c1 = q1[1];
        union { bf16x8 v; unsigned short s[8]; } t;
        t.s[0]=f2bf(a0[0]); t.s[1]=f2bf(a0[1]); t.s[2]=f2bf(a0[2]); t.s[3]=f2bf(a0[3]);
        t.s[4]=f2bf(a1[0]); t.s[5]=f2bf(a1[1]); t.s[6]=f2bf(a1[2]); t.s[7]=f2bf(a1[3]);
        b0 = t.v;
        t.s[0]=f2bf(c0[0]); t.s[1]=f2bf(c0[1]); t.s[2]=f2bf(c0[2]); t.s[3]=f2bf(c0[3]);
        t.s[4]=f2bf(c1[0]); t.s[5]=f2bf(c1[1]); t.s[6]=f2bf(c1[2]); t.s[7]=f2bf(c1[3]);
        b1 = t.v;
      }
      acc0 = __builtin_amdgcn_mfma_f32_16x16x32_bf16(af, b0, acc0, 0, 0, 0);
      acc1 = __builtin_amdgcn_mfma_f32_16x16x32_bf16(af, b1, acc1, 0, 0, 0);
    }

    if (c + 1 < NCHUNK){
      sA0 = sB0; sA1 = sB1; uA0 = uB0; uA1 = uB1; xA0 = xB0; xA1 = xB1;
    }
  }

  // epilogue: C/D layout col=lane&15, row=(lane>>4)*4+reg; 4-way K-split
  // partials combined with f32 HW atomics (out pre-zeroed by hipMemsetAsync)
  const int colBase = wv * 32 + (l & 15);
  const int r0      = rowBase + ((l >> 4) << 2);
  #pragma unroll
  for (int rg = 0; rg < 4; ++rg){
    unsafeAtomicAdd(&out[(size_t)(r0 + rg) * OUT_F + colBase],      acc0[rg]);
    unsafeAtomicAdd(&out[(size_t)(r0 + rg) * OUT_F + colBase + 16], acc1[rg]);
  }
}

extern "C" void kernel_launch(void* const* d_in, const int* in_sizes, int n_in,
                              void* d_out, int out_size, void* d_ws, size_t ws_size,
                              hipStream_t stream){
  const float* pre = (const float*)d_in[0];
  const float* w   = (const float*)d_in[1];
  const float* u   = (const float*)d_in[2];
  const float* x   = (const float*)d_in[3];
  float* out    = (float*)d_out;
  float* un_out = out + (size_t)BATCH * OUT_F;
  float* xn_out = un_out + (size_t)BATCH * IN_F;
  unsigned short* wf = (unsigned short*)d_ws;

  // zero the GEMM output region (atomic accumulation target)
  hipMemsetAsync(out, 0, (size_t)BATCH * OUT_F * sizeof(float), stream);

  const bool use_ws = (ws_size >= (size_t)(1 << 20));   // identical to R1/R2/R4
  const int grid = (BATCH / 16) * KSPLIT;               // 2048 blocks
  if (use_ws){
    prep_weight_kernel<<<256, 256, 0, stream>>>(w, wf);
    stp_fused4<true><<<grid, 256, 0, stream>>>(pre, u, x, w, wf, out, un_out, xn_out);
  } else {
    stp_fused4<false><<<grid, 256, 0, stream>>>(pre, u, x, w, nullptr, out, un_out, xn_out);
  }
}

// Round 8
// 160.258 us; speedup vs baseline: 2.0221x; 1.0188x over previous
//
#include <hip/hip_runtime.h>
#include <hip/hip_bf16.h>
#include <cstdint>

#define BATCH 8192
#define IN_F  4096
#define OUT_F 128
#define ROWS  16
#define KEXT  2048       // k-extent per block (KSPLIT=2)
// float32-rounded decay constants (tau_fac=100, tau_dep=200)
#define FD 0.99004983374916811f
#define DD 0.99501247919268232f

typedef __attribute__((ext_vector_type(4))) float f32x4;
typedef __attribute__((ext_vector_type(8))) short bf16x8;

__device__ __forceinline__ unsigned short f2bf(float f){
  union { float f; unsigned u; } v; v.f = f;
  unsigned u = v.u;
  return (unsigned short)((u + 0x7FFFu + ((u >> 16) & 1u)) >> 16);  // RNE
}

// Pre-shuffle weight[128][4096] f32 -> fragment-major bf16 (proven R1-R7).
// Frag id f = (ks*8 + ct)*64 + l ; lane l holds weight[ct*16+(l&15)][ks*32+(l>>4)*8 + j]
__global__ __launch_bounds__(256) void prep_weight_kernel(const float* __restrict__ w,
                                                          unsigned short* __restrict__ wf){
  const int f  = blockIdx.x * 256 + threadIdx.x;   // 0..65535
  const int l  = f & 63;
  const int ct = (f >> 6) & 7;
  const int ks = f >> 9;                           // 0..127
  const int row = ct * 16 + (l & 15);
  const int k   = ks * 32 + ((l >> 4) << 3);
  const f32x4* src = reinterpret_cast<const f32x4*>(w + (size_t)row * IN_F + k);
  f32x4 a = src[0], b = src[1];
  union { bf16x8 v; unsigned short s[8]; } o;
  o.s[0]=f2bf(a[0]); o.s[1]=f2bf(a[1]); o.s[2]=f2bf(a[2]); o.s[3]=f2bf(a[3]);
  o.s[4]=f2bf(b[0]); o.s[5]=f2bf(b[1]); o.s[6]=f2bf(b[2]); o.s[7]=f2bf(b[3]);
  *reinterpret_cast<bf16x8*>(wf + (size_t)f * 8) = o.v;
}

// Phase-A/phase-B fused kernel, ONE sequential stream-head per array per block.
// Block = 1024 thr = 16 waves, owns 16 consecutive rows x 2048-k half (KSPLIT=2).
// Phase A: sweep tile 2 rows at a time (1024 thr x f32x4 = 8KB contiguous per
// array per step) -> minimal DRAM stream concurrency. STP math in regs, un/xn
// stored same pattern, r=u*x*s packed bf16 into XOR-swizzled 64KB LDS tile.
// Phase B: wave w -> col-tile w&7, k-half w>>3; A-frags from LDS, B from wf;
// 2-way K-split partials via f32 HW atomics (out pre-zeroed).
template<bool WS>
__global__ __launch_bounds__(1024, 8) void stp_fused5(
    const float* __restrict__ pre, const float* __restrict__ uin,
    const float* __restrict__ xin, const float* __restrict__ w,
    const unsigned short* __restrict__ wf,
    float* __restrict__ out, float* __restrict__ un_out, float* __restrict__ xn_out)
{
  __shared__ unsigned char rbuf[ROWS * KEXT * 2];   // 64 KB -> 2 blocks/CU

  const int tid = threadIdx.x;
  const int w64 = tid >> 6;                 // wave 0..15
  const int l   = tid & 63;
  const int kspl    = blockIdx.x & 1;
  const int rowBase = (blockIdx.x >> 1) * ROWS;
  const int k0      = kspl * KEXT;

  // ---------------- phase A ----------------
  const int rof = tid >> 9;                 // row within pair (0/1)
  const int kk  = (tid & 511) << 2;         // float index within KEXT

  f32x4 sC, uC, xC, sN, uN, xN;
  {
    const size_t g0 = (size_t)(rowBase + rof) * IN_F + k0 + kk;
    sC = *reinterpret_cast<const f32x4*>(pre + g0);
    uC = *reinterpret_cast<const f32x4*>(uin + g0);
    xC = *reinterpret_cast<const f32x4*>(xin + g0);
  }

  #pragma unroll
  for (int rp = 0; rp < 8; ++rp){
    const int row = rp * 2 + rof;
    const size_t g = (size_t)(rowBase + row) * IN_F + k0 + kk;

    // prefetch next row-pair (one step of slack; TLP covers the rest)
    if (rp < 7){
      const size_t gn = g + (size_t)2 * IN_F;
      sN = *reinterpret_cast<const f32x4*>(pre + gn);
      uN = *reinterpret_cast<const f32x4*>(uin + gn);
      xN = *reinterpret_cast<const f32x4*>(xin + gn);
    }

    f32x4 un, xn;
    unsigned short rb[4];
    #pragma unroll
    for (int j = 0; j < 4; ++j){
      const float s = sC[j], u = uC[j], x = xC[j];
      rb[j] = f2bf(u * x * s);
      const float ufd = u * FD;
      const float unj = __builtin_fmaf(0.5f * s, 1.0f - ufd, ufd);
      un[j] = unj;
      // xn = DD - DD*(s*un)*(1-x)  (algebraically == reference)
      xn[j] = __builtin_fmaf((s * unj) * (1.0f - x), -DD, DD);
    }
    *reinterpret_cast<f32x4*>(un_out + g) = un;
    *reinterpret_cast<f32x4*>(xn_out + g) = xn;

    uint2 pk;
    pk.x = (unsigned)rb[0] | ((unsigned)rb[1] << 16);
    pk.y = (unsigned)rb[2] | ((unsigned)rb[3] << 16);
    // LDS: row-major [16][2048] bf16, byte addr XOR-swizzled in bits 4-6
    const int wb = ((row << 12) + (kk << 1)) ^ ((row & 7) << 4);
    *reinterpret_cast<uint2*>(rbuf + wb) = pk;

    sC = sN; uC = uN; xC = xN;
  }

  __syncthreads();

  // ---------------- phase B ----------------
  const int ct = w64 & 7;                   // col-tile 0..7
  const int kh = w64 >> 3;                  // k-half 0/1
  const bf16x8* wfp = reinterpret_cast<const bf16x8*>(wf);

  f32x4 acc = {0.f, 0.f, 0.f, 0.f};
  #pragma unroll 4
  for (int ks = 0; ks < 32; ++ks){
    const int lks = (kh << 5) + ks;         // local k-step 0..63
    // A-frag: lane l -> row l&15, k = lks*32 + (l>>4)*8 ; same swizzle as write
    const int ab = (((l & 15) << 12) + (lks << 6) + ((l >> 4) << 4)) ^ ((l & 7) << 4);
    bf16x8 af = *reinterpret_cast<const bf16x8*>(rbuf + ab);

    const int gks = (kspl << 6) + lks;      // global k-step 0..127
    bf16x8 bfv;
    if (WS){
      bfv = wfp[(size_t)((gks * 8 + ct) << 6) + l];
    } else {
      const int kg = gks * 32 + ((l >> 4) << 3);
      const int r0w = ct * 16 + (l & 15);
      const f32x4* p = reinterpret_cast<const f32x4*>(w + (size_t)r0w * IN_F + kg);
      f32x4 a = p[0], b = p[1];
      union { bf16x8 v; unsigned short s[8]; } t;
      t.s[0]=f2bf(a[0]); t.s[1]=f2bf(a[1]); t.s[2]=f2bf(a[2]); t.s[3]=f2bf(a[3]);
      t.s[4]=f2bf(b[0]); t.s[5]=f2bf(b[1]); t.s[6]=f2bf(b[2]); t.s[7]=f2bf(b[3]);
      bfv = t.v;
    }
    acc = __builtin_amdgcn_mfma_f32_16x16x32_bf16(af, bfv, acc, 0, 0, 0);
  }

  // epilogue: C/D layout col=lane&15, row=(lane>>4)*4+reg.
  // 4 contributors per out element (2 k-halves x 2 kspl blocks) via HW atomics.
  const int col = ct * 16 + (l & 15);
  const int r0  = rowBase + ((l >> 4) << 2);
  #pragma unroll
  for (int rg = 0; rg < 4; ++rg){
    unsafeAtomicAdd(&out[(size_t)(r0 + rg) * OUT_F + col], acc[rg]);
  }
}

extern "C" void kernel_launch(void* const* d_in, const int* in_sizes, int n_in,
                              void* d_out, int out_size, void* d_ws, size_t ws_size,
                              hipStream_t stream){
  const float* pre = (const float*)d_in[0];
  const float* w   = (const float*)d_in[1];
  const float* u   = (const float*)d_in[2];
  const float* x   = (const float*)d_in[3];
  float* out    = (float*)d_out;
  float* un_out = out + (size_t)BATCH * OUT_F;
  float* xn_out = un_out + (size_t)BATCH * IN_F;
  unsigned short* wf = (unsigned short*)d_ws;

  // zero the GEMM output region (atomic accumulation target)
  hipMemsetAsync(out, 0, (size_t)BATCH * OUT_F * sizeof(float), stream);

  const bool use_ws = (ws_size >= (size_t)(1 << 20));   // same gate as R1-R7
  const int grid = (BATCH / ROWS) * 2;                  // 1024 blocks
  if (use_ws){
    prep_weight_kernel<<<256, 256, 0, stream>>>(w, wf);
    stp_fused5<true><<<grid, 1024, 0, stream>>>(pre, u, x, w, wf, out, un_out, xn_out);
  } else {
    stp_fused5<false><<<grid, 1024, 0, stream>>>(pre, u, x, w, nullptr, out, un_out, xn_out);
  }
}